// Round 12
// baseline (442.616 us; speedup 1.0000x reference)
//
#include <hip/hip_runtime.h>
#include <cstdint>
#include <cstddef>

// ---------- types ----------
typedef __attribute__((ext_vector_type(8)))  __bf16 bf16x8;
typedef __attribute__((ext_vector_type(4)))  __bf16 bf16x4;
typedef __attribute__((ext_vector_type(4)))  float  f32x4;
typedef __attribute__((ext_vector_type(16))) float  f32x16;
typedef __attribute__((ext_vector_type(2)))  uint32_t u32x2;
typedef __attribute__((ext_vector_type(4)))  uint32_t u32x4;

#define MFMA32(a, b, c) __builtin_amdgcn_mfma_f32_32x32x16_bf16((a), (b), (c), 0, 0, 0)

// async global->LDS, 16B per lane. LDS dest must be wave-uniform base + lane*16.
__device__ __forceinline__ void gload_lds16(const __bf16* src, __bf16* lds_dst) {
    __builtin_amdgcn_global_load_lds(
        (const __attribute__((address_space(1))) void*)(const_cast<__bf16*>(src)),
        (__attribute__((address_space(3))) void*)(lds_dst), 16, 0, 0);
}

__device__ __forceinline__ uint32_t pack2(float a, float b) {
    uint16_t ua = __builtin_bit_cast(uint16_t, (__bf16)a);
    uint16_t ub = __builtin_bit_cast(uint16_t, (__bf16)b);
    return (uint32_t)ua | ((uint32_t)ub << 16);
}

// XCD-chunked bijective block swizzle (requires n%8==0).
__device__ __forceinline__ int xcd_swz(int lid, int n) {
    return (lid & 7) * (n >> 3) + (lid >> 3);
}

// ---------- fused fp32 -> bf16 convert (all 4 weights, one launch) ----------
__global__ __launch_bounds__(256) void cvt4_kernel(const float* __restrict__ s0,
                                                   const float* __restrict__ s1,
                                                   const float* __restrict__ s2,
                                                   const float* __restrict__ s3,
                                                   __bf16* __restrict__ d0,
                                                   __bf16* __restrict__ d1,
                                                   __bf16* __restrict__ d2,
                                                   __bf16* __restrict__ d3) {
    int b = blockIdx.x;
    const float* s; __bf16* d; int off;
    if (b < 3072)       { s = s0; d = d0; off = b; }
    else if (b < 4096)  { s = s1; d = d1; off = b - 3072; }
    else if (b < 12288) { s = s2; d = d2; off = b - 4096; }
    else                { s = s3; d = d3; off = b - 12288; }
    int i = off * 256 + threadIdx.x;
    float4 v = reinterpret_cast<const float4*>(s)[i];
    bf16x4 o;
    o[0] = (__bf16)v.x; o[1] = (__bf16)v.y; o[2] = (__bf16)v.z; o[3] = (__bf16)v.w;
    reinterpret_cast<bf16x4*>(d)[i] = o;
}

// ---------- RMSNorm (row = 1024 fp32) -> bf16 ----------
__global__ __launch_bounds__(256) void rmsnorm_kernel(const float* __restrict__ x,
                                                      const float* __restrict__ g,
                                                      __bf16* __restrict__ out) {
    const int row = blockIdx.x;
    const int t = threadIdx.x;
    float4 v = reinterpret_cast<const float4*>(x + (size_t)row * 1024)[t];
    float ss = v.x * v.x + v.y * v.y + v.z * v.z + v.w * v.w;
#pragma unroll
    for (int m = 1; m < 64; m <<= 1) ss += __shfl_xor(ss, m);
    __shared__ float sred[4];
    if ((t & 63) == 0) sred[t >> 6] = ss;
    __syncthreads();
    float tot = sred[0] + sred[1] + sred[2] + sred[3];
    float rs = rsqrtf(tot * (1.0f / 1024.0f) + 1.1920928955078125e-07f);
    float4 gv = reinterpret_cast<const float4*>(g)[t];
    bf16x4 o;
    o[0] = (__bf16)(v.x * rs * gv.x);
    o[1] = (__bf16)(v.y * rs * gv.y);
    o[2] = (__bf16)(v.z * rs * gv.z);
    o[3] = (__bf16)(v.w * rs * gv.w);
    *reinterpret_cast<bf16x4*>(out + (size_t)row * 1024 + t * 4) = o;
}

// ---------- RMSNorm (row = 1024 bf16) -> bf16 ----------
__global__ __launch_bounds__(256) void rmsnorm_b_kernel(const __bf16* __restrict__ x,
                                                        const float* __restrict__ g,
                                                        __bf16* __restrict__ out) {
    const int row = blockIdx.x;
    const int t = threadIdx.x;
    bf16x4 v4 = reinterpret_cast<const bf16x4*>(x + (size_t)row * 1024)[t];
    float a = (float)v4[0], b = (float)v4[1], c = (float)v4[2], d = (float)v4[3];
    float ss = a * a + b * b + c * c + d * d;
#pragma unroll
    for (int m = 1; m < 64; m <<= 1) ss += __shfl_xor(ss, m);
    __shared__ float sred[4];
    if ((t & 63) == 0) sred[t >> 6] = ss;
    __syncthreads();
    float tot = sred[0] + sred[1] + sred[2] + sred[3];
    float rs = rsqrtf(tot * (1.0f / 1024.0f) + 1.1920928955078125e-07f);
    float4 gv = reinterpret_cast<const float4*>(g)[t];
    bf16x4 o;
    o[0] = (__bf16)(a * rs * gv.x);
    o[1] = (__bf16)(b * rs * gv.y);
    o[2] = (__bf16)(c * rs * gv.z);
    o[3] = (__bf16)(d * rs * gv.w);
    *reinterpret_cast<bf16x4*>(out + (size_t)row * 1024 + t * 4) = o;
}

// ---------- NT GEMM (32x32x16 MFMA, chunk-major LDS): C = A B^T ----------
// tile 128 x (BN32*32), BK=64, 4 waves (2x2): per-wave 64 x (BN32*16).
// LDS layout [k-chunk][row][8 elems]: fragment reads are lane-CONSECUTIVE 16B
// -> zero bank conflicts under any phase model. Achieved by re-pointing the
// per-lane global source (LDS dest linear, rule #21).
// MODE 0: out bf16.
// MODE 1: out bf16 = acc + f32 resid            (o-proj -> x2 bf16)
// MODE 2: FFN1+SwiGLU fused (B rows permuted via srow; pair cols via shfl_xor(1)).
// MODE 3: out f32 = acc + bf16 resid            (ffn2 -> final out)
// MODE 4: qkv: Q,K cols (bn<16) -> outb; V cols (bn>=16) transposed -> vt[bh][hd][n]
// SQ: 1 = square 16x16 XCD chunk mapping (grid 32x64), else stripe swizzle.
template <int MODE, int BN32, int SQ>
__global__ __launch_bounds__(256) void gemm_nt(const __bf16* __restrict__ A, int lda,
                                               const __bf16* __restrict__ B, int ldb,
                                               __bf16* __restrict__ outb,
                                               float* __restrict__ outf,
                                               const float* __restrict__ resid,
                                               const __bf16* __restrict__ residb,
                                               __bf16* __restrict__ vt,
                                               int K, int ldo) {
    constexpr int BN = BN32 * 32;
    constexpr int NBW = BN32 / 2;          // n-blocks of 32 per wave
    constexpr int BSH = (BN == 128) ? 7 : 6;   // log2(BN)
    __shared__ __attribute__((aligned(16))) __bf16 As[128 * 64];  // [8][128][8]
    __shared__ __attribute__((aligned(16))) __bf16 Bs[BN * 64];   // [8][BN][8]
    const int t = threadIdx.x;
    const int lane = t & 63;
    const int wid = t >> 6;
    const int hi = lane >> 5;
    const int l31 = lane & 31;
    int bm, bn;
    if (SQ) {   // square 16x16 chunks per XCD (grid must be 32x64)
        int lid = blockIdx.x + blockIdx.y * gridDim.x;
        int c = lid & 7, i = lid >> 3;
        bm = (c & 1) * 16 + (i & 15);
        bn = (c >> 1) * 16 + (i >> 4);
    } else {
        int nwg = gridDim.x * gridDim.y;
        int sid = xcd_swz(blockIdx.x + blockIdx.y * gridDim.x, nwg);
        bm = sid % gridDim.x; bn = sid / gridDim.x;
    }
    const int wm = (wid >> 1) * 64, wn = (wid & 1) * (BN / 2);

    // staging source pointers (chunk-major slot mapping), += 64 elems per K-tile
    const __bf16* pa[4];
    const __bf16* pb[BN32];
#pragma unroll
    for (int i = 0; i < 4; ++i) {
        int L = i * 256 + t, r = L & 127, c = L >> 7;
        pa[i] = A + (size_t)(bm * 128 + r) * lda + c * 8;
    }
#pragma unroll
    for (int i = 0; i < BN32; ++i) {
        int L = i * 256 + t, r = L & (BN - 1), c = L >> BSH;
        int rb = bn * BN + r;
        int srow = (MODE == 2) ? ((rb >> 1) + ((rb & 1) << 12)) : rb;
        pb[i] = B + (size_t)srow * ldb + c * 8;
    }

    // fragment LDS element-offsets: chunk (kk*2+hi), row -> consecutive lanes
    uint32_t aoff[2][4], boff[NBW][4];
#pragma unroll
    for (int mi = 0; mi < 2; ++mi)
#pragma unroll
        for (int kk = 0; kk < 4; ++kk)
            aoff[mi][kk] = (kk * 2 + hi) * 1024 + (wm + mi * 32 + l31) * 8;
#pragma unroll
    for (int ni = 0; ni < NBW; ++ni)
#pragma unroll
        for (int kk = 0; kk < 4; ++kk)
            boff[ni][kk] = (kk * 2 + hi) * (BN * 8) + (wn + ni * 32 + l31) * 8;

    f32x16 acc[2][NBW] = {};

    for (int kt = 0; kt < K; kt += 64) {
        __syncthreads();
#pragma unroll
        for (int i = 0; i < 4; ++i) {
            gload_lds16(pa[i], As + (i * 256 + t) * 8);
            pa[i] += 64;
        }
#pragma unroll
        for (int i = 0; i < BN32; ++i) {
            gload_lds16(pb[i], Bs + (i * 256 + t) * 8);
            pb[i] += 64;
        }
        __syncthreads();
#pragma unroll
        for (int kk = 0; kk < 4; ++kk) {
            bf16x8 af[2], bfr[NBW];
#pragma unroll
            for (int mi = 0; mi < 2; ++mi)
                af[mi] = *reinterpret_cast<const bf16x8*>(As + aoff[mi][kk]);
#pragma unroll
            for (int ni = 0; ni < NBW; ++ni)
                bfr[ni] = *reinterpret_cast<const bf16x8*>(Bs + boff[ni][kk]);
            __builtin_amdgcn_s_setprio(1);
#pragma unroll
            for (int mi = 0; mi < 2; ++mi)
#pragma unroll
                for (int ni = 0; ni < NBW; ++ni)
                    acc[mi][ni] = MFMA32(af[mi], bfr[ni], acc[mi][ni]);
            __builtin_amdgcn_s_setprio(0);
        }
    }

    // epilogue: C/D 32x32 layout: col = l31, row = (r&3) + 8*(r>>2) + 4*hi
    const int row0 = bm * 128 + wm + 4 * hi;
    const int col0 = bn * BN + wn + l31;
    if (MODE == 4 && bn >= 16) {
        // V path: write transposed to vt[bh][hd][n]; rows r&3 are consecutive n
#pragma unroll
        for (int mi = 0; mi < 2; ++mi)
#pragma unroll
            for (int ni = 0; ni < NBW; ++ni)
#pragma unroll
                for (int g = 0; g < 4; ++g) {
                    bf16x4 o4;
#pragma unroll
                    for (int j = 0; j < 4; ++j) o4[j] = (__bf16)acc[mi][ni][g * 4 + j];
                    int n0 = row0 + mi * 32 + 8 * g;
                    int bb = n0 >> 11, nn = n0 & 2047;
                    int vc = col0 + ni * 32 - 2048;
                    *reinterpret_cast<bf16x4*>(
                        vt + ((size_t)(bb * 16 + (vc >> 6)) * 64 + (vc & 63)) * 2048 + nn) = o4;
                }
        return;
    }
#pragma unroll
    for (int mi = 0; mi < 2; ++mi)
#pragma unroll
        for (int ni = 0; ni < NBW; ++ni)
#pragma unroll
            for (int r = 0; r < 16; ++r) {
                int row = row0 + mi * 32 + (r & 3) + 8 * (r >> 2);
                int col = col0 + ni * 32;
                float v = acc[mi][ni][r];
                size_t idx = (size_t)row * ldo + col;
                if (MODE == 0 || MODE == 4) {
                    outb[idx] = (__bf16)v;
                } else if (MODE == 1) {
                    outb[idx] = (__bf16)(v + resid[idx]);
                } else if (MODE == 3) {
                    outf[idx] = v + (float)residb[idx];
                } else {
                    float pv = __shfl_xor(v, 1);
                    if (!(lane & 1)) {
                        float sg = v / (1.0f + __expf(-v));
                        outb[(size_t)row * ldo + (col >> 1)] = (__bf16)(sg * pv);
                    }
                }
            }
}

// ---------- flash attention v7: fixed-base + KV-split-2 + chunk-major LDS ----------
// grid (16, 32, 2): z = KV half. Single-buffered 32KB LDS (4 blocks/CU).
// Ks [8 chunk][128 seq][8], Vs [16 chunk][64 hd][8]: fragment reads lane-consecutive.
__global__ __launch_bounds__(256) void attn_kernel(const __bf16* __restrict__ qkv,
                                                   const __bf16* __restrict__ vt,
                                                   float* __restrict__ opart,
                                                   float* __restrict__ lpart) {
    __shared__ __attribute__((aligned(16))) __bf16 Ks[128 * 64];
    __shared__ __attribute__((aligned(16))) __bf16 Vs[64 * 128];
    const int t = threadIdx.x;
    const int lane = t & 63;
    const int w = t >> 6;
    const int hi = lane >> 5;
    const int l31 = lane & 31;
    const int nwg = gridDim.x * gridDim.y;
    const int sid = xcd_swz(blockIdx.x + blockIdx.y * gridDim.x, nwg);
    const int qb = sid % gridDim.x;
    const int bh = sid / gridDim.x;
    const int kz = blockIdx.z;
    const int b = bh >> 4, h = bh & 15;
    const __bf16* qp = qkv + (size_t)b * 2048 * 3072 + h * 64;
    const __bf16* kp = qp + 1024;
    const __bf16* vtp = vt + (size_t)bh * 64 * 2048;
    const int q0 = qb * 128 + w * 32;

    const float SC = 0.18033688011112042f;   // (1/8) * log2(e)
    bf16x8 qf[4];
#pragma unroll
    for (int s = 0; s < 4; ++s) {
        bf16x8 raw = *reinterpret_cast<const bf16x8*>(
            qp + (size_t)(q0 + l31) * 3072 + s * 16 + hi * 8);
        bf16x8 sc;
#pragma unroll
        for (int j = 0; j < 8; ++j) sc[j] = (__bf16)((float)raw[j] * SC);
        qf[s] = sc;
    }

    f32x16 oa[2] = {};
    float l_run = 0.0f;

    auto stage = [&](int kt) {
#pragma unroll
        for (int i = 0; i < 4; ++i) {   // K: slot L = c*128 + r (c: hd-chunk, r: seq)
            int L = i * 256 + t;
            int c = L >> 7, r = L & 127;
            gload_lds16(kp + (size_t)(kt + r) * 3072 + c * 8, &Ks[L * 8]);
        }
#pragma unroll
        for (int i = 0; i < 4; ++i) {   // V^T: slot L = c*64 + hd (c: seq-chunk)
            int L = i * 256 + t;
            int c = L >> 6, hd = L & 63;
            gload_lds16(vtp + (size_t)hd * 2048 + kt + c * 8, &Vs[L * 8]);
        }
    };

    const int kt0 = kz * 1024;
    for (int kt = kt0; kt < kt0 + 1024; kt += 128) {
        stage(kt);
        asm volatile("s_waitcnt vmcnt(0)\n\ts_barrier" ::: "memory");

#pragma unroll
        for (int h2 = 0; h2 < 2; ++h2) {
            f32x16 st[2];
#pragma unroll
            for (int r = 0; r < 16; ++r) { st[0][r] = -6.0f; st[1][r] = -6.0f; }
            __builtin_amdgcn_s_setprio(1);
#pragma unroll
            for (int s = 0; s < 4; ++s) {
#pragma unroll
                for (int mb = 0; mb < 2; ++mb) {
                    bf16x8 kf = *reinterpret_cast<const bf16x8*>(
                        &Ks[(s * 2 + hi) * 1024 + (h2 * 64 + mb * 32 + l31) * 8]);
                    st[mb] = MFMA32(kf, qf[s], st[mb]);
                }
            }
            __builtin_amdgcn_s_setprio(0);

            // fixed-base: P = exp2(st) (st biased by -6 via C-in)
            float ps = 0.0f;
#pragma unroll
            for (int mb = 0; mb < 2; ++mb)
#pragma unroll
                for (int r = 0; r < 16; ++r) {
                    float p = exp2f(st[mb][r]);
                    st[mb][r] = p;
                    ps += p;
                }
            ps += __shfl_xor(ps, 32);
            l_run += ps;

            uint32_t pk[16];
#pragma unroll
            for (int mb = 0; mb < 2; ++mb)
#pragma unroll
                for (int i2 = 0; i2 < 8; ++i2)
                    pk[mb * 8 + i2] = pack2(st[mb][2 * i2], st[mb][2 * i2 + 1]);

            __builtin_amdgcn_s_setprio(1);
#pragma unroll
            for (int s2 = 0; s2 < 4; ++s2) {
                const int I0 = (s2 >> 1) * 8 + (s2 & 1) * 4;
                u32x2 w02 = __builtin_amdgcn_permlane32_swap(pk[I0], pk[I0 + 2], false, false);
                u32x2 w13 = __builtin_amdgcn_permlane32_swap(pk[I0 + 1], pk[I0 + 3], false, false);
                u32x4 fv;
                fv[0] = w02[0]; fv[1] = w13[0]; fv[2] = w02[1]; fv[3] = w13[1];
                bf16x8 pa = __builtin_bit_cast(bf16x8, fv);
#pragma unroll
                for (int nb = 0; nb < 2; ++nb) {
                    bf16x8 vf = *reinterpret_cast<const bf16x8*>(
                        &Vs[(h2 * 8 + s2 * 2 + hi) * 512 + (nb * 32 + l31) * 8]);
                    oa[nb] = MFMA32(pa, vf, oa[nb]);
                }
            }
            __builtin_amdgcn_s_setprio(0);
        }
        __syncthreads();   // all reads done before next stage overwrites
    }

    // store UNNORMALIZED partials (linear combine later)
#pragma unroll
    for (int r = 0; r < 16; ++r) {
        int crow = (r & 3) + 8 * (r >> 2) + 4 * hi;
        int row = q0 + crow;
        size_t base = (size_t)kz * 4194304 + ((size_t)b * 2048 + row) * 1024 + h * 64 + l31;
        opart[base]      = oa[0][r];
        opart[base + 32] = oa[1][r];
    }
    if (hi == 0)
        lpart[kz * 65536 + bh * 2048 + q0 + l31] = l_run;
}

// ---------- attention combine: o = (p0+p1) / (l0+l1) ----------
__global__ __launch_bounds__(256) void attn_comb(const float* __restrict__ op,
                                                 const float* __restrict__ lp,
                                                 __bf16* __restrict__ o) {
    const int row = blockIdx.x;            // b*2048 + q
    const int t = threadIdx.x;
    const int b = row >> 11, q = row & 2047;
    const int c0 = t * 4;
    const int h = c0 >> 6;
    const int li = (b * 16 + h) * 2048 + q;
    float l = lp[li] + lp[65536 + li];
    float inv = 1.0f / l;
    float4 p0 = *reinterpret_cast<const float4*>(op + (size_t)row * 1024 + c0);
    float4 p1 = *reinterpret_cast<const float4*>(op + 4194304 + (size_t)row * 1024 + c0);
    bf16x4 o4;
    o4[0] = (__bf16)((p0.x + p1.x) * inv);
    o4[1] = (__bf16)((p0.y + p1.y) * inv);
    o4[2] = (__bf16)((p0.z + p1.z) * inv);
    o4[3] = (__bf16)((p0.w + p1.w) * inv);
    *reinterpret_cast<bf16x4*>(o + (size_t)row * 1024 + c0) = o4;
}

// ---------- launch ----------
extern "C" void kernel_launch(void* const* d_in, const int* in_sizes, int n_in,
                              void* d_out, int out_size, void* d_ws, size_t ws_size,
                              hipStream_t stream) {
    const float* x      = (const float*)d_in[0];
    const float* w_qkv  = (const float*)d_in[3];
    const float* w_o    = (const float*)d_in[4];
    const float* w1     = (const float*)d_in[5];
    const float* w2     = (const float*)d_in[6];
    const float* g_attn = (const float*)d_in[7];
    const float* g_ff   = (const float*)d_in[8];
    float* out = (float*)d_out;

    char* ws = (char*)d_ws;
    size_t off = 0;
    auto alloc = [&](size_t bytes) -> void* {
        void* p = ws + off;
        off += (bytes + 255) & ~(size_t)255;
        return p;
    };
    __bf16* wqkv_b = (__bf16*)alloc((size_t)3072 * 1024 * 2);
    __bf16* wo_b   = (__bf16*)alloc((size_t)1024 * 1024 * 2);
    __bf16* w1_b   = (__bf16*)alloc((size_t)8192 * 1024 * 2);
    __bf16* w2_b   = (__bf16*)alloc((size_t)1024 * 4096 * 2);
    __bf16* h_b    = (__bf16*)alloc((size_t)4096 * 1024 * 2);
    __bf16* qkv_b  = (__bf16*)alloc((size_t)4096 * 3072 * 2);
    __bf16* o_b    = (__bf16*)alloc((size_t)4096 * 1024 * 2);
    __bf16* x2b    = (__bf16*)alloc((size_t)4096 * 1024 * 2);
    __bf16* vt_b   = (__bf16*)alloc((size_t)32 * 64 * 2048 * 2);
    float*  opart  = (float*)alloc((size_t)2 * 4096 * 1024 * 4);
    float*  lpart  = (float*)alloc((size_t)2 * 32 * 2048 * 4);
    __bf16* act_b  = qkv_b;  // alias: act over qkv (qkv dead after attn)

    cvt4_kernel<<<16384, 256, 0, stream>>>(w_qkv, w_o, w1, w2,
                                           wqkv_b, wo_b, w1_b, w2_b);

    rmsnorm_kernel<<<4096, 256, 0, stream>>>(x, g_attn, h_b);
    // qkv: Q,K -> qkv_b; V transposed -> vt_b (fused)
    gemm_nt<4, 4, 0><<<dim3(32, 24), 256, 0, stream>>>(h_b, 1024, wqkv_b, 1024,
                                                       qkv_b, nullptr, nullptr, nullptr,
                                                       vt_b, 1024, 3072);
    // attention: KV-split-2, fixed-base partials + linear combine
    attn_kernel<<<dim3(16, 32, 2), 256, 0, stream>>>(qkv_b, vt_b, opart, lpart);
    attn_comb<<<4096, 256, 0, stream>>>(opart, lpart, o_b);
    // o-proj: x2b (bf16) = o @ w_o^T + x
    gemm_nt<1, 2, 0><<<dim3(32, 16), 256, 0, stream>>>(o_b, 1024, wo_b, 1024,
                                                       x2b, nullptr, x, nullptr,
                                                       nullptr, 1024, 1024);
    rmsnorm_b_kernel<<<4096, 256, 0, stream>>>(x2b, g_ff, h_b);
    // ffn1: 128x128 tiles + fused SwiGLU, square 16x16 XCD chunks
    gemm_nt<2, 4, 1><<<dim3(32, 64), 256, 0, stream>>>(h_b, 1024, w1_b, 1024,
                                                       act_b, nullptr, nullptr, nullptr,
                                                       nullptr, 1024, 4096);
    // ffn2: 128x64 tiles, 512 blocks, out = act @ w2^T + x2b
    gemm_nt<3, 2, 0><<<dim3(32, 16), 256, 0, stream>>>(act_b, 4096, w2_b, 4096,
                                                       nullptr, out, nullptr, x2b,
                                                       nullptr, 4096, 1024);
}

// Round 13
// 342.036 us; speedup vs baseline: 1.2941x; 1.2941x over previous
//
#include <hip/hip_runtime.h>
#include <cstdint>
#include <cstddef>

// ---------- types ----------
typedef __attribute__((ext_vector_type(8)))  __bf16 bf16x8;
typedef __attribute__((ext_vector_type(4)))  __bf16 bf16x4;
typedef __attribute__((ext_vector_type(4)))  float  f32x4;
typedef __attribute__((ext_vector_type(16))) float  f32x16;
typedef __attribute__((ext_vector_type(2)))  uint32_t u32x2;
typedef __attribute__((ext_vector_type(4)))  uint32_t u32x4;

#define MFMA_BF16(a, b, c) __builtin_amdgcn_mfma_f32_16x16x32_bf16((a), (b), (c), 0, 0, 0)
#define MFMA32(a, b, c)    __builtin_amdgcn_mfma_f32_32x32x16_bf16((a), (b), (c), 0, 0, 0)

// async global->LDS, 16B per lane. LDS dest must be wave-uniform base + lane*16.
__device__ __forceinline__ void gload_lds16(const __bf16* src, __bf16* lds_dst) {
    __builtin_amdgcn_global_load_lds(
        (const __attribute__((address_space(1))) void*)(const_cast<__bf16*>(src)),
        (__attribute__((address_space(3))) void*)(lds_dst), 16, 0, 0);
}

__device__ __forceinline__ uint32_t pack2(float a, float b) {
    uint16_t ua = __builtin_bit_cast(uint16_t, (__bf16)a);
    uint16_t ub = __builtin_bit_cast(uint16_t, (__bf16)b);
    return (uint32_t)ua | ((uint32_t)ub << 16);
}

// XCD-chunked bijective block swizzle (requires n%8==0).
__device__ __forceinline__ int xcd_swz(int lid, int n) {
    return (lid & 7) * (n >> 3) + (lid >> 3);
}

// ---------- fused fp32 -> bf16 convert (all 4 weights, one launch) ----------
__global__ __launch_bounds__(256) void cvt4_kernel(const float* __restrict__ s0,
                                                   const float* __restrict__ s1,
                                                   const float* __restrict__ s2,
                                                   const float* __restrict__ s3,
                                                   __bf16* __restrict__ d0,
                                                   __bf16* __restrict__ d1,
                                                   __bf16* __restrict__ d2,
                                                   __bf16* __restrict__ d3) {
    int b = blockIdx.x;
    const float* s; __bf16* d; int off;
    if (b < 3072)       { s = s0; d = d0; off = b; }
    else if (b < 4096)  { s = s1; d = d1; off = b - 3072; }
    else if (b < 12288) { s = s2; d = d2; off = b - 4096; }
    else                { s = s3; d = d3; off = b - 12288; }
    int i = off * 256 + threadIdx.x;
    float4 v = reinterpret_cast<const float4*>(s)[i];
    bf16x4 o;
    o[0] = (__bf16)v.x; o[1] = (__bf16)v.y; o[2] = (__bf16)v.z; o[3] = (__bf16)v.w;
    reinterpret_cast<bf16x4*>(d)[i] = o;
}

// ---------- RMSNorm (row = 1024 fp32) -> bf16 ----------
__global__ __launch_bounds__(256) void rmsnorm_kernel(const float* __restrict__ x,
                                                      const float* __restrict__ g,
                                                      __bf16* __restrict__ out) {
    const int row = blockIdx.x;
    const int t = threadIdx.x;
    float4 v = reinterpret_cast<const float4*>(x + (size_t)row * 1024)[t];
    float ss = v.x * v.x + v.y * v.y + v.z * v.z + v.w * v.w;
#pragma unroll
    for (int m = 1; m < 64; m <<= 1) ss += __shfl_xor(ss, m);
    __shared__ float sred[4];
    if ((t & 63) == 0) sred[t >> 6] = ss;
    __syncthreads();
    float tot = sred[0] + sred[1] + sred[2] + sred[3];
    float rs = rsqrtf(tot * (1.0f / 1024.0f) + 1.1920928955078125e-07f);
    float4 gv = reinterpret_cast<const float4*>(g)[t];
    bf16x4 o;
    o[0] = (__bf16)(v.x * rs * gv.x);
    o[1] = (__bf16)(v.y * rs * gv.y);
    o[2] = (__bf16)(v.z * rs * gv.z);
    o[3] = (__bf16)(v.w * rs * gv.w);
    *reinterpret_cast<bf16x4*>(out + (size_t)row * 1024 + t * 4) = o;
}

// ---------- RMSNorm (row = 1024 bf16) -> bf16 ----------
__global__ __launch_bounds__(256) void rmsnorm_b_kernel(const __bf16* __restrict__ x,
                                                        const float* __restrict__ g,
                                                        __bf16* __restrict__ out) {
    const int row = blockIdx.x;
    const int t = threadIdx.x;
    bf16x4 v4 = reinterpret_cast<const bf16x4*>(x + (size_t)row * 1024)[t];
    float a = (float)v4[0], b = (float)v4[1], c = (float)v4[2], d = (float)v4[3];
    float ss = a * a + b * b + c * c + d * d;
#pragma unroll
    for (int m = 1; m < 64; m <<= 1) ss += __shfl_xor(ss, m);
    __shared__ float sred[4];
    if ((t & 63) == 0) sred[t >> 6] = ss;
    __syncthreads();
    float tot = sred[0] + sred[1] + sred[2] + sred[3];
    float rs = rsqrtf(tot * (1.0f / 1024.0f) + 1.1920928955078125e-07f);
    float4 gv = reinterpret_cast<const float4*>(g)[t];
    bf16x4 o;
    o[0] = (__bf16)(a * rs * gv.x);
    o[1] = (__bf16)(b * rs * gv.y);
    o[2] = (__bf16)(c * rs * gv.z);
    o[3] = (__bf16)(d * rs * gv.w);
    *reinterpret_cast<bf16x4*>(out + (size_t)row * 1024 + t * 4) = o;
}

// ---------- NT GEMM (16x16x32 MFMA, R9 structure + incremented staging ptrs) ----------
// tile 128 x (NB*32), BK=64, 4 waves (2x2): per-wave 64 x (NB*16).
// Fragment pattern: 16 rows x 4 k-chunks per lane-group -> measured 0 bank conflicts
// (32-row-span b128 reads are INHERENTLY 4-way conflicted at 128B rows; 16-row
//  pattern is the structural fix — R10-R12 lesson).
// MODE 0: out bf16.
// MODE 1: out bf16 = acc + f32 resid            (o-proj -> x2 bf16)
// MODE 2: FFN1+SwiGLU fused (B rows permuted via srow; pair cols via shfl_xor(1)).
// MODE 3: out f32 = acc + bf16 resid            (ffn2 -> final out)
// MODE 4: qkv: Q,K cols (bn<16) -> outb; V cols (bn>=16) transposed -> vt[bh][hd][n]
// SQ: 1 = square 16x16 XCD chunk mapping (grid 32x64), else stripe swizzle.
template <int MODE, int NB, int SQ>
__global__ __launch_bounds__(256) void gemm_nt(const __bf16* __restrict__ A, int lda,
                                               const __bf16* __restrict__ B, int ldb,
                                               __bf16* __restrict__ outb,
                                               float* __restrict__ outf,
                                               const float* __restrict__ resid,
                                               const __bf16* __restrict__ residb,
                                               __bf16* __restrict__ vt,
                                               int K, int ldo) {
    constexpr int BN = NB * 32;
    __shared__ __attribute__((aligned(16))) __bf16 As[128 * 64];
    __shared__ __attribute__((aligned(16))) __bf16 Bs[BN * 64];
    const int t = threadIdx.x;
    const int lane = t & 63;
    const int wid = t >> 6;
    int bm, bn;
    if (SQ) {   // square 16x16 chunks per XCD (grid must be 32x64)
        int lid = blockIdx.x + blockIdx.y * gridDim.x;
        int c = lid & 7, i = lid >> 3;
        bm = (c & 1) * 16 + (i & 15);
        bn = (c >> 1) * 16 + (i >> 4);
    } else {
        int nwg = gridDim.x * gridDim.y;
        int sid = xcd_swz(blockIdx.x + blockIdx.y * gridDim.x, nwg);
        bm = sid % gridDim.x; bn = sid / gridDim.x;
    }
    const int wm = (wid >> 1) * 64, wn = (wid & 1) * (NB * 16);

    // staging source pointers: computed once, += 64 elems per K-tile (VALU saver)
    const __bf16* pa[4];
    const __bf16* pb[NB];
#pragma unroll
    for (int i = 0; i < 4; ++i) {
        int L = i * 256 + t, r = L >> 3, c = (L & 7) ^ (r & 7);
        pa[i] = A + (size_t)(bm * 128 + r) * lda + c * 8;
    }
#pragma unroll
    for (int i = 0; i < NB; ++i) {
        int L = i * 256 + t, r = L >> 3, c = (L & 7) ^ (r & 7);
        int rb = bn * BN + r;
        int srow = (MODE == 2) ? ((rb >> 1) + ((rb & 1) << 12)) : rb;
        pb[i] = B + (size_t)srow * ldb + c * 8;
    }

    f32x4 acc[4][NB] = {};

    for (int kt = 0; kt < K; kt += 64) {
        __syncthreads();
#pragma unroll
        for (int i = 0; i < 4; ++i) {
            gload_lds16(pa[i], As + (i * 256 + t) * 8);
            pa[i] += 64;
        }
#pragma unroll
        for (int i = 0; i < NB; ++i) {
            gload_lds16(pb[i], Bs + (i * 256 + t) * 8);
            pb[i] += 64;
        }
        __syncthreads();
#pragma unroll
        for (int ks = 0; ks < 2; ++ks) {
            bf16x8 af[4], bfr[NB];
#pragma unroll
            for (int mi = 0; mi < 4; ++mi) {
                int r = wm + mi * 16 + (lane & 15);
                int slot = (ks * 4 + (lane >> 4)) ^ (r & 7);
                af[mi] = *reinterpret_cast<const bf16x8*>(As + r * 64 + slot * 8);
            }
#pragma unroll
            for (int ni = 0; ni < NB; ++ni) {
                int r = wn + ni * 16 + (lane & 15);
                int slot = (ks * 4 + (lane >> 4)) ^ (r & 7);
                bfr[ni] = *reinterpret_cast<const bf16x8*>(Bs + r * 64 + slot * 8);
            }
            __builtin_amdgcn_s_setprio(1);
#pragma unroll
            for (int mi = 0; mi < 4; ++mi)
#pragma unroll
                for (int ni = 0; ni < NB; ++ni)
                    acc[mi][ni] = MFMA_BF16(af[mi], bfr[ni], acc[mi][ni]);
            __builtin_amdgcn_s_setprio(0);
        }
    }
    const int row0 = bm * 128 + wm + ((lane >> 4) << 2);
    const int col0 = bn * BN + wn + (lane & 15);
    if (MODE == 4 && bn >= 16) {
        // V path: write transposed to vt[bh][hd][n]; rows r2 are consecutive n
#pragma unroll
        for (int mi = 0; mi < 4; ++mi)
#pragma unroll
            for (int ni = 0; ni < NB; ++ni) {
                bf16x4 o4;
#pragma unroll
                for (int r2 = 0; r2 < 4; ++r2) o4[r2] = (__bf16)acc[mi][ni][r2];
                int n0 = row0 + mi * 16;
                int bb = n0 >> 11, nn = n0 & 2047;
                int vc = col0 + ni * 16 - 2048;
                *reinterpret_cast<bf16x4*>(
                    vt + ((size_t)(bb * 16 + (vc >> 6)) * 64 + (vc & 63)) * 2048 + nn) = o4;
            }
        return;
    }
#pragma unroll
    for (int mi = 0; mi < 4; ++mi)
#pragma unroll
        for (int ni = 0; ni < NB; ++ni)
#pragma unroll
            for (int r2 = 0; r2 < 4; ++r2) {
                int row = row0 + mi * 16 + r2;
                int col = col0 + ni * 16;
                float v = acc[mi][ni][r2];
                size_t idx = (size_t)row * ldo + col;
                if (MODE == 0 || MODE == 4) {
                    outb[idx] = (__bf16)v;
                } else if (MODE == 1) {
                    outb[idx] = (__bf16)(v + resid[idx]);
                } else if (MODE == 3) {
                    outf[idx] = v + (float)residb[idx];
                } else {
                    float pv = __shfl_xor(v, 1);
                    if (!(lane & 1)) {
                        float sg = v / (1.0f + __expf(-v));
                        outb[(size_t)row * ldo + (col >> 1)] = (__bf16)(sg * pv);
                    }
                }
            }
}

// ---------- flash attention v5 (R9): fixed-base softmax + KV-split-2 ----------
// grid (16, 32, 2): z = KV half. Single-buffered 32KB LDS (4 blocks/CU).
// Partials are LINEAR (fixed base, no max): opart = sum P*V (bf16), lpart = sum P (f32).
__global__ __launch_bounds__(256) void attn_kernel(const __bf16* __restrict__ qkv,
                                                   const __bf16* __restrict__ vt,
                                                   __bf16* __restrict__ opart,
                                                   float* __restrict__ lpart) {
    __shared__ __attribute__((aligned(16))) __bf16 Ks[128 * 64];
    __shared__ __attribute__((aligned(16))) __bf16 Vs[64 * 128];
    const int t = threadIdx.x;
    const int lane = t & 63;
    const int w = t >> 6;
    const int hi = lane >> 5;
    const int l31 = lane & 31;
    const int nwg = gridDim.x * gridDim.y;
    const int sid = xcd_swz(blockIdx.x + blockIdx.y * gridDim.x, nwg);
    const int qb = sid % gridDim.x;
    const int bh = sid / gridDim.x;
    const int kz = blockIdx.z;
    const int b = bh >> 4, h = bh & 15;
    const __bf16* qp = qkv + (size_t)b * 2048 * 3072 + h * 64;
    const __bf16* kp = qp + 1024;
    const __bf16* vtp = vt + (size_t)bh * 64 * 2048;
    const int q0 = qb * 128 + w * 32;

    const float SC = 0.18033688011112042f;   // (1/8) * log2(e)
    bf16x8 qf[4];
#pragma unroll
    for (int s = 0; s < 4; ++s) {
        bf16x8 raw = *reinterpret_cast<const bf16x8*>(
            qp + (size_t)(q0 + l31) * 3072 + s * 16 + hi * 8);
        bf16x8 sc;
#pragma unroll
        for (int j = 0; j < 8; ++j) sc[j] = (__bf16)((float)raw[j] * SC);
        qf[s] = sc;
    }

    f32x16 oa[2] = {};
    float l_run = 0.0f;

    auto stage = [&](int kt) {
#pragma unroll
        for (int i = 0; i < 4; ++i) {
            int L = i * 256 + t;
            int r = L >> 3, s = L & 7;
            int c = s ^ (r & 7);
            gload_lds16(kp + (size_t)(kt + r) * 3072 + c * 8, &Ks[L * 8]);
        }
#pragma unroll
        for (int i = 0; i < 4; ++i) {
            int L = i * 256 + t;
            int r = L >> 4, s = L & 15;
            int c = s ^ (r & 15);
            gload_lds16(vtp + (size_t)r * 2048 + kt + c * 8, &Vs[L * 8]);
        }
    };

    const int kt0 = kz * 1024;
    for (int kt = kt0; kt < kt0 + 1024; kt += 128) {
        stage(kt);
        asm volatile("s_waitcnt vmcnt(0)\n\ts_barrier" ::: "memory");

#pragma unroll
        for (int h2 = 0; h2 < 2; ++h2) {
            f32x16 st[2];
#pragma unroll
            for (int r = 0; r < 16; ++r) { st[0][r] = -6.0f; st[1][r] = -6.0f; }
            __builtin_amdgcn_s_setprio(1);
#pragma unroll
            for (int s = 0; s < 4; ++s) {
#pragma unroll
                for (int mb = 0; mb < 2; ++mb) {
                    int r = h2 * 64 + mb * 32 + l31;
                    int sl = (s * 2 + hi) ^ (r & 7);
                    bf16x8 kf = *reinterpret_cast<const bf16x8*>(&Ks[r * 64 + sl * 8]);
                    st[mb] = MFMA32(kf, qf[s], st[mb]);
                }
            }
            __builtin_amdgcn_s_setprio(0);

            // fixed-base: P = exp2(st) (st biased by -6 via C-in)
            float ps = 0.0f;
#pragma unroll
            for (int mb = 0; mb < 2; ++mb)
#pragma unroll
                for (int r = 0; r < 16; ++r) {
                    float p = exp2f(st[mb][r]);
                    st[mb][r] = p;
                    ps += p;
                }
            ps += __shfl_xor(ps, 32);
            l_run += ps;

            uint32_t pk[16];
#pragma unroll
            for (int mb = 0; mb < 2; ++mb)
#pragma unroll
                for (int i2 = 0; i2 < 8; ++i2)
                    pk[mb * 8 + i2] = pack2(st[mb][2 * i2], st[mb][2 * i2 + 1]);

            __builtin_amdgcn_s_setprio(1);
#pragma unroll
            for (int s2 = 0; s2 < 4; ++s2) {
                const int I0 = (s2 >> 1) * 8 + (s2 & 1) * 4;
                u32x2 w02 = __builtin_amdgcn_permlane32_swap(pk[I0], pk[I0 + 2], false, false);
                u32x2 w13 = __builtin_amdgcn_permlane32_swap(pk[I0 + 1], pk[I0 + 3], false, false);
                u32x4 fv;
                fv[0] = w02[0]; fv[1] = w13[0]; fv[2] = w02[1]; fv[3] = w13[1];
                bf16x8 pa = __builtin_bit_cast(bf16x8, fv);
#pragma unroll
                for (int nb = 0; nb < 2; ++nb) {
                    int rv = nb * 32 + l31;
                    int ch = h2 * 8 + s2 * 2 + hi;
                    int sl = ch ^ (rv & 15);
                    bf16x8 vf = *reinterpret_cast<const bf16x8*>(&Vs[rv * 128 + sl * 8]);
                    oa[nb] = MFMA32(pa, vf, oa[nb]);
                }
            }
            __builtin_amdgcn_s_setprio(0);
        }
        __syncthreads();   // all reads done before next stage overwrites
    }

    // store UNNORMALIZED partials as bf16 (linear combine later; l stays f32)
#pragma unroll
    for (int r = 0; r < 16; ++r) {
        int crow = (r & 3) + 8 * (r >> 2) + 4 * hi;
        int row = q0 + crow;
        size_t base = (size_t)kz * 4194304 + ((size_t)b * 2048 + row) * 1024 + h * 64 + l31;
        opart[base]      = (__bf16)oa[0][r];
        opart[base + 32] = (__bf16)oa[1][r];
    }
    if (hi == 0)
        lpart[kz * 65536 + bh * 2048 + q0 + l31] = l_run;
}

// ---------- attention combine: o = (p0+p1) / (l0+l1) ----------
__global__ __launch_bounds__(256) void attn_comb(const __bf16* __restrict__ op,
                                                 const float* __restrict__ lp,
                                                 __bf16* __restrict__ o) {
    const int row = blockIdx.x;            // b*2048 + q
    const int t = threadIdx.x;
    const int b = row >> 11, q = row & 2047;
    const int c0 = t * 4;
    const int h = c0 >> 6;
    const int li = (b * 16 + h) * 2048 + q;
    float l = lp[li] + lp[65536 + li];
    float inv = 1.0f / l;
    bf16x4 p0 = *reinterpret_cast<const bf16x4*>(op + (size_t)row * 1024 + c0);
    bf16x4 p1 = *reinterpret_cast<const bf16x4*>(op + 4194304 + (size_t)row * 1024 + c0);
    bf16x4 o4;
#pragma unroll
    for (int j = 0; j < 4; ++j)
        o4[j] = (__bf16)(((float)p0[j] + (float)p1[j]) * inv);
    *reinterpret_cast<bf16x4*>(o + (size_t)row * 1024 + c0) = o4;
}

// ---------- launch ----------
extern "C" void kernel_launch(void* const* d_in, const int* in_sizes, int n_in,
                              void* d_out, int out_size, void* d_ws, size_t ws_size,
                              hipStream_t stream) {
    const float* x      = (const float*)d_in[0];
    const float* w_qkv  = (const float*)d_in[3];
    const float* w_o    = (const float*)d_in[4];
    const float* w1     = (const float*)d_in[5];
    const float* w2     = (const float*)d_in[6];
    const float* g_attn = (const float*)d_in[7];
    const float* g_ff   = (const float*)d_in[8];
    float* out = (float*)d_out;

    char* ws = (char*)d_ws;
    size_t off = 0;
    auto alloc = [&](size_t bytes) -> void* {
        void* p = ws + off;
        off += (bytes + 255) & ~(size_t)255;
        return p;
    };
    __bf16* wqkv_b = (__bf16*)alloc((size_t)3072 * 1024 * 2);
    __bf16* wo_b   = (__bf16*)alloc((size_t)1024 * 1024 * 2);
    __bf16* w1_b   = (__bf16*)alloc((size_t)8192 * 1024 * 2);
    __bf16* w2_b   = (__bf16*)alloc((size_t)1024 * 4096 * 2);
    __bf16* h_b    = (__bf16*)alloc((size_t)4096 * 1024 * 2);
    __bf16* qkv_b  = (__bf16*)alloc((size_t)4096 * 3072 * 2);
    __bf16* o_b    = (__bf16*)alloc((size_t)4096 * 1024 * 2);
    __bf16* x2b    = (__bf16*)alloc((size_t)4096 * 1024 * 2);
    __bf16* vt_b   = (__bf16*)alloc((size_t)32 * 64 * 2048 * 2);
    __bf16* opart  = (__bf16*)alloc((size_t)2 * 4096 * 1024 * 2);
    float*  lpart  = (float*)alloc((size_t)2 * 32 * 2048 * 4);
    __bf16* act_b  = qkv_b;  // alias: act over qkv (qkv dead after attn)

    cvt4_kernel<<<16384, 256, 0, stream>>>(w_qkv, w_o, w1, w2,
                                           wqkv_b, wo_b, w1_b, w2_b);

    rmsnorm_kernel<<<4096, 256, 0, stream>>>(x, g_attn, h_b);
    // qkv: Q,K -> qkv_b; V transposed -> vt_b (fused)
    gemm_nt<4, 4, 0><<<dim3(32, 24), 256, 0, stream>>>(h_b, 1024, wqkv_b, 1024,
                                                       qkv_b, nullptr, nullptr, nullptr,
                                                       vt_b, 1024, 3072);
    // attention: KV-split-2, fixed-base partials + linear combine
    attn_kernel<<<dim3(16, 32, 2), 256, 0, stream>>>(qkv_b, vt_b, opart, lpart);
    attn_comb<<<4096, 256, 0, stream>>>(opart, lpart, o_b);
    // o-proj: x2b (bf16) = o @ w_o^T + x
    gemm_nt<1, 2, 0><<<dim3(32, 16), 256, 0, stream>>>(o_b, 1024, wo_b, 1024,
                                                       x2b, nullptr, x, nullptr,
                                                       nullptr, 1024, 1024);
    rmsnorm_b_kernel<<<4096, 256, 0, stream>>>(x2b, g_ff, h_b);
    // ffn1: 128x128 tiles + fused SwiGLU, square 16x16 XCD chunks
    gemm_nt<2, 4, 1><<<dim3(32, 64), 256, 0, stream>>>(h_b, 1024, w1_b, 1024,
                                                       act_b, nullptr, nullptr, nullptr,
                                                       nullptr, 1024, 4096);
    // ffn2: 128x64 tiles, 512 blocks, out = act @ w2^T + x2b
    gemm_nt<3, 2, 0><<<dim3(32, 16), 256, 0, stream>>>(act_b, 4096, w2_b, 4096,
                                                       nullptr, out, nullptr, x2b,
                                                       nullptr, 4096, 1024);
}

// Round 14
// 307.595 us; speedup vs baseline: 1.4390x; 1.1120x over previous
//
#include <hip/hip_runtime.h>
#include <cstdint>
#include <cstddef>

// ---------- types ----------
typedef __attribute__((ext_vector_type(8)))  __bf16 bf16x8;
typedef __attribute__((ext_vector_type(4)))  __bf16 bf16x4;
typedef __attribute__((ext_vector_type(4)))  float  f32x4;
typedef __attribute__((ext_vector_type(16))) float  f32x16;
typedef __attribute__((ext_vector_type(2)))  uint32_t u32x2;
typedef __attribute__((ext_vector_type(4)))  uint32_t u32x4;

#define MFMA_BF16(a, b, c) __builtin_amdgcn_mfma_f32_16x16x32_bf16((a), (b), (c), 0, 0, 0)
#define MFMA32(a, b, c)    __builtin_amdgcn_mfma_f32_32x32x16_bf16((a), (b), (c), 0, 0, 0)

// async global->LDS, 16B per lane. LDS dest must be wave-uniform base + lane*16.
__device__ __forceinline__ void gload_lds16(const __bf16* src, __bf16* lds_dst) {
    __builtin_amdgcn_global_load_lds(
        (const __attribute__((address_space(1))) void*)(const_cast<__bf16*>(src)),
        (__attribute__((address_space(3))) void*)(lds_dst), 16, 0, 0);
}

__device__ __forceinline__ uint32_t pack2(float a, float b) {
    uint16_t ua = __builtin_bit_cast(uint16_t, (__bf16)a);
    uint16_t ub = __builtin_bit_cast(uint16_t, (__bf16)b);
    return (uint32_t)ua | ((uint32_t)ub << 16);
}

// XCD-chunked bijective block swizzle (requires n%8==0).
__device__ __forceinline__ int xcd_swz(int lid, int n) {
    return (lid & 7) * (n >> 3) + (lid >> 3);
}

// ---------- fused fp32 -> bf16 convert (all 4 weights, one launch) ----------
__global__ __launch_bounds__(256) void cvt4_kernel(const float* __restrict__ s0,
                                                   const float* __restrict__ s1,
                                                   const float* __restrict__ s2,
                                                   const float* __restrict__ s3,
                                                   __bf16* __restrict__ d0,
                                                   __bf16* __restrict__ d1,
                                                   __bf16* __restrict__ d2,
                                                   __bf16* __restrict__ d3) {
    int b = blockIdx.x;
    const float* s; __bf16* d; int off;
    if (b < 3072)       { s = s0; d = d0; off = b; }
    else if (b < 4096)  { s = s1; d = d1; off = b - 3072; }
    else if (b < 12288) { s = s2; d = d2; off = b - 4096; }
    else                { s = s3; d = d3; off = b - 12288; }
    int i = off * 256 + threadIdx.x;
    float4 v = reinterpret_cast<const float4*>(s)[i];
    bf16x4 o;
    o[0] = (__bf16)v.x; o[1] = (__bf16)v.y; o[2] = (__bf16)v.z; o[3] = (__bf16)v.w;
    reinterpret_cast<bf16x4*>(d)[i] = o;
}

// ---------- RMSNorm (row = 1024 fp32) -> bf16 ----------
__global__ __launch_bounds__(256) void rmsnorm_kernel(const float* __restrict__ x,
                                                      const float* __restrict__ g,
                                                      __bf16* __restrict__ out) {
    const int row = blockIdx.x;
    const int t = threadIdx.x;
    float4 v = reinterpret_cast<const float4*>(x + (size_t)row * 1024)[t];
    float ss = v.x * v.x + v.y * v.y + v.z * v.z + v.w * v.w;
#pragma unroll
    for (int m = 1; m < 64; m <<= 1) ss += __shfl_xor(ss, m);
    __shared__ float sred[4];
    if ((t & 63) == 0) sred[t >> 6] = ss;
    __syncthreads();
    float tot = sred[0] + sred[1] + sred[2] + sred[3];
    float rs = rsqrtf(tot * (1.0f / 1024.0f) + 1.1920928955078125e-07f);
    float4 gv = reinterpret_cast<const float4*>(g)[t];
    bf16x4 o;
    o[0] = (__bf16)(v.x * rs * gv.x);
    o[1] = (__bf16)(v.y * rs * gv.y);
    o[2] = (__bf16)(v.z * rs * gv.z);
    o[3] = (__bf16)(v.w * rs * gv.w);
    *reinterpret_cast<bf16x4*>(out + (size_t)row * 1024 + t * 4) = o;
}

// ---------- RMSNorm (row = 1024 bf16) -> bf16 ----------
__global__ __launch_bounds__(256) void rmsnorm_b_kernel(const __bf16* __restrict__ x,
                                                        const float* __restrict__ g,
                                                        __bf16* __restrict__ out) {
    const int row = blockIdx.x;
    const int t = threadIdx.x;
    bf16x4 v4 = reinterpret_cast<const bf16x4*>(x + (size_t)row * 1024)[t];
    float a = (float)v4[0], b = (float)v4[1], c = (float)v4[2], d = (float)v4[3];
    float ss = a * a + b * b + c * c + d * d;
#pragma unroll
    for (int m = 1; m < 64; m <<= 1) ss += __shfl_xor(ss, m);
    __shared__ float sred[4];
    if ((t & 63) == 0) sred[t >> 6] = ss;
    __syncthreads();
    float tot = sred[0] + sred[1] + sred[2] + sred[3];
    float rs = rsqrtf(tot * (1.0f / 1024.0f) + 1.1920928955078125e-07f);
    float4 gv = reinterpret_cast<const float4*>(g)[t];
    bf16x4 o;
    o[0] = (__bf16)(a * rs * gv.x);
    o[1] = (__bf16)(b * rs * gv.y);
    o[2] = (__bf16)(c * rs * gv.z);
    o[3] = (__bf16)(d * rs * gv.w);
    *reinterpret_cast<bf16x4*>(out + (size_t)row * 1024 + t * 4) = o;
}

// ---------- NT GEMM (16x16x32 MFMA, R9-exact): C[m,n] = sum_k A[m,k] * B[n,k] ----------
// tile 128 x (NB*32), BK=64, 4 waves (2x2): per-wave 64 x (NB*16).
// In-loop address computation (NOT hoisted pointers): VGPR 76, occupancy ~28%.
// R13 lesson: hoisting staging pointers costs +20 VGPR -> occupancy 28->21% -> −25%.
// This kernel family is occupancy-sensitive above all.
// MODE 0: out bf16.
// MODE 1: out bf16 = acc + f32 resid            (o-proj -> x2 bf16)
// MODE 2: FFN1+SwiGLU fused (B rows permuted via srow; pair cols via shfl_xor(1)).
// MODE 3: out f32 = acc + bf16 resid            (ffn2 -> final out)
// MODE 4: qkv: Q,K cols (bn<16) -> outb; V cols (bn>=16) transposed -> vt[bh][hd][n]
// SQ: 1 = square 16x16 XCD chunk mapping (grid 32x64), else stripe swizzle.
template <int MODE, int NB, int SQ>
__global__ __launch_bounds__(256) void gemm_nt(const __bf16* __restrict__ A, int lda,
                                               const __bf16* __restrict__ B, int ldb,
                                               __bf16* __restrict__ outb,
                                               float* __restrict__ outf,
                                               const float* __restrict__ resid,
                                               const __bf16* __restrict__ residb,
                                               __bf16* __restrict__ vt,
                                               int K, int ldo) {
    constexpr int BN = NB * 32;
    __shared__ __attribute__((aligned(16))) __bf16 As[128 * 64];
    __shared__ __attribute__((aligned(16))) __bf16 Bs[BN * 64];
    const int t = threadIdx.x;
    const int lane = t & 63;
    const int wid = t >> 6;
    int bm, bn;
    if (SQ) {   // square 16x16 chunks per XCD (grid must be 32x64)
        int lid = blockIdx.x + blockIdx.y * gridDim.x;
        int c = lid & 7, i = lid >> 3;
        bm = (c & 1) * 16 + (i & 15);
        bn = (c >> 1) * 16 + (i >> 4);
    } else {
        int nwg = gridDim.x * gridDim.y;
        int sid = xcd_swz(blockIdx.x + blockIdx.y * gridDim.x, nwg);
        bm = sid % gridDim.x; bn = sid / gridDim.x;
    }
    const int wm = (wid >> 1) * 64, wn = (wid & 1) * (NB * 16);
    f32x4 acc[4][NB] = {};

    for (int kt = 0; kt < K; kt += 64) {
        __syncthreads();
#pragma unroll
        for (int i = 0; i < 4; ++i) {
            int L = i * 256 + t;
            int r = L >> 3, s = L & 7;
            int c = s ^ (r & 7);
            gload_lds16(A + (size_t)(bm * 128 + r) * lda + kt + c * 8, As + L * 8);
        }
#pragma unroll
        for (int i = 0; i < NB; ++i) {
            int L = i * 256 + t;
            int r = L >> 3, s = L & 7;
            int c = s ^ (r & 7);
            int rb = bn * BN + r;
            int srow = (MODE == 2) ? ((rb >> 1) + ((rb & 1) << 12)) : rb;
            gload_lds16(B + (size_t)srow * ldb + kt + c * 8, Bs + L * 8);
        }
        __syncthreads();
#pragma unroll
        for (int ks = 0; ks < 2; ++ks) {
            bf16x8 af[4], bfr[NB];
#pragma unroll
            for (int mi = 0; mi < 4; ++mi) {
                int r = wm + mi * 16 + (lane & 15);
                int slot = (ks * 4 + (lane >> 4)) ^ (r & 7);
                af[mi] = *reinterpret_cast<const bf16x8*>(As + r * 64 + slot * 8);
            }
#pragma unroll
            for (int ni = 0; ni < NB; ++ni) {
                int r = wn + ni * 16 + (lane & 15);
                int slot = (ks * 4 + (lane >> 4)) ^ (r & 7);
                bfr[ni] = *reinterpret_cast<const bf16x8*>(Bs + r * 64 + slot * 8);
            }
            __builtin_amdgcn_s_setprio(1);
#pragma unroll
            for (int mi = 0; mi < 4; ++mi)
#pragma unroll
                for (int ni = 0; ni < NB; ++ni)
                    acc[mi][ni] = MFMA_BF16(af[mi], bfr[ni], acc[mi][ni]);
            __builtin_amdgcn_s_setprio(0);
        }
    }
    const int row0 = bm * 128 + wm + ((lane >> 4) << 2);
    const int col0 = bn * BN + wn + (lane & 15);
    if (MODE == 4 && bn >= 16) {
        // V path: write transposed to vt[bh][hd][n]; rows r2 are consecutive n
#pragma unroll
        for (int mi = 0; mi < 4; ++mi)
#pragma unroll
            for (int ni = 0; ni < NB; ++ni) {
                bf16x4 o4;
#pragma unroll
                for (int r2 = 0; r2 < 4; ++r2) o4[r2] = (__bf16)acc[mi][ni][r2];
                int n0 = row0 + mi * 16;
                int bb = n0 >> 11, nn = n0 & 2047;
                int vc = col0 + ni * 16 - 2048;
                *reinterpret_cast<bf16x4*>(
                    vt + ((size_t)(bb * 16 + (vc >> 6)) * 64 + (vc & 63)) * 2048 + nn) = o4;
            }
        return;
    }
#pragma unroll
    for (int mi = 0; mi < 4; ++mi)
#pragma unroll
        for (int ni = 0; ni < NB; ++ni)
#pragma unroll
            for (int r2 = 0; r2 < 4; ++r2) {
                int row = row0 + mi * 16 + r2;
                int col = col0 + ni * 16;
                float v = acc[mi][ni][r2];
                size_t idx = (size_t)row * ldo + col;
                if (MODE == 0 || MODE == 4) {
                    outb[idx] = (__bf16)v;
                } else if (MODE == 1) {
                    outb[idx] = (__bf16)(v + resid[idx]);
                } else if (MODE == 3) {
                    outf[idx] = v + (float)residb[idx];
                } else {
                    float pv = __shfl_xor(v, 1);
                    if (!(lane & 1)) {
                        float sg = v / (1.0f + __expf(-v));
                        outb[(size_t)row * ldo + (col >> 1)] = (__bf16)(sg * pv);
                    }
                }
            }
}

// ---------- flash attention v5 (R9): fixed-base softmax + KV-split-2 ----------
// grid (16, 32, 2): z = KV half. Single-buffered 32KB LDS (4 blocks/CU).
// Partials are LINEAR (fixed base, no max): opart = sum P*V (bf16), lpart = sum P (f32).
__global__ __launch_bounds__(256) void attn_kernel(const __bf16* __restrict__ qkv,
                                                   const __bf16* __restrict__ vt,
                                                   __bf16* __restrict__ opart,
                                                   float* __restrict__ lpart) {
    __shared__ __attribute__((aligned(16))) __bf16 Ks[128 * 64];
    __shared__ __attribute__((aligned(16))) __bf16 Vs[64 * 128];
    const int t = threadIdx.x;
    const int lane = t & 63;
    const int w = t >> 6;
    const int hi = lane >> 5;
    const int l31 = lane & 31;
    const int nwg = gridDim.x * gridDim.y;
    const int sid = xcd_swz(blockIdx.x + blockIdx.y * gridDim.x, nwg);
    const int qb = sid % gridDim.x;
    const int bh = sid / gridDim.x;
    const int kz = blockIdx.z;
    const int b = bh >> 4, h = bh & 15;
    const __bf16* qp = qkv + (size_t)b * 2048 * 3072 + h * 64;
    const __bf16* kp = qp + 1024;
    const __bf16* vtp = vt + (size_t)bh * 64 * 2048;
    const int q0 = qb * 128 + w * 32;

    const float SC = 0.18033688011112042f;   // (1/8) * log2(e)
    bf16x8 qf[4];
#pragma unroll
    for (int s = 0; s < 4; ++s) {
        bf16x8 raw = *reinterpret_cast<const bf16x8*>(
            qp + (size_t)(q0 + l31) * 3072 + s * 16 + hi * 8);
        bf16x8 sc;
#pragma unroll
        for (int j = 0; j < 8; ++j) sc[j] = (__bf16)((float)raw[j] * SC);
        qf[s] = sc;
    }

    f32x16 oa[2] = {};
    float l_run = 0.0f;

    auto stage = [&](int kt) {
#pragma unroll
        for (int i = 0; i < 4; ++i) {
            int L = i * 256 + t;
            int r = L >> 3, s = L & 7;
            int c = s ^ (r & 7);
            gload_lds16(kp + (size_t)(kt + r) * 3072 + c * 8, &Ks[L * 8]);
        }
#pragma unroll
        for (int i = 0; i < 4; ++i) {
            int L = i * 256 + t;
            int r = L >> 4, s = L & 15;
            int c = s ^ (r & 15);
            gload_lds16(vtp + (size_t)r * 2048 + kt + c * 8, &Vs[L * 8]);
        }
    };

    const int kt0 = kz * 1024;
    for (int kt = kt0; kt < kt0 + 1024; kt += 128) {
        stage(kt);
        asm volatile("s_waitcnt vmcnt(0)\n\ts_barrier" ::: "memory");

#pragma unroll
        for (int h2 = 0; h2 < 2; ++h2) {
            f32x16 st[2];
#pragma unroll
            for (int r = 0; r < 16; ++r) { st[0][r] = -6.0f; st[1][r] = -6.0f; }
            __builtin_amdgcn_s_setprio(1);
#pragma unroll
            for (int s = 0; s < 4; ++s) {
#pragma unroll
                for (int mb = 0; mb < 2; ++mb) {
                    int r = h2 * 64 + mb * 32 + l31;
                    int sl = (s * 2 + hi) ^ (r & 7);
                    bf16x8 kf = *reinterpret_cast<const bf16x8*>(&Ks[r * 64 + sl * 8]);
                    st[mb] = MFMA32(kf, qf[s], st[mb]);
                }
            }
            __builtin_amdgcn_s_setprio(0);

            // fixed-base: P = exp2(st) (st biased by -6 via C-in)
            float ps = 0.0f;
#pragma unroll
            for (int mb = 0; mb < 2; ++mb)
#pragma unroll
                for (int r = 0; r < 16; ++r) {
                    float p = exp2f(st[mb][r]);
                    st[mb][r] = p;
                    ps += p;
                }
            ps += __shfl_xor(ps, 32);
            l_run += ps;

            uint32_t pk[16];
#pragma unroll
            for (int mb = 0; mb < 2; ++mb)
#pragma unroll
                for (int i2 = 0; i2 < 8; ++i2)
                    pk[mb * 8 + i2] = pack2(st[mb][2 * i2], st[mb][2 * i2 + 1]);

            __builtin_amdgcn_s_setprio(1);
#pragma unroll
            for (int s2 = 0; s2 < 4; ++s2) {
                const int I0 = (s2 >> 1) * 8 + (s2 & 1) * 4;
                u32x2 w02 = __builtin_amdgcn_permlane32_swap(pk[I0], pk[I0 + 2], false, false);
                u32x2 w13 = __builtin_amdgcn_permlane32_swap(pk[I0 + 1], pk[I0 + 3], false, false);
                u32x4 fv;
                fv[0] = w02[0]; fv[1] = w13[0]; fv[2] = w02[1]; fv[3] = w13[1];
                bf16x8 pa = __builtin_bit_cast(bf16x8, fv);
#pragma unroll
                for (int nb = 0; nb < 2; ++nb) {
                    int rv = nb * 32 + l31;
                    int ch = h2 * 8 + s2 * 2 + hi;
                    int sl = ch ^ (rv & 15);
                    bf16x8 vf = *reinterpret_cast<const bf16x8*>(&Vs[rv * 128 + sl * 8]);
                    oa[nb] = MFMA32(pa, vf, oa[nb]);
                }
            }
            __builtin_amdgcn_s_setprio(0);
        }
        __syncthreads();   // all reads done before next stage overwrites
    }

    // store UNNORMALIZED partials as bf16 (linear combine later; l stays f32)
#pragma unroll
    for (int r = 0; r < 16; ++r) {
        int crow = (r & 3) + 8 * (r >> 2) + 4 * hi;
        int row = q0 + crow;
        size_t base = (size_t)kz * 4194304 + ((size_t)b * 2048 + row) * 1024 + h * 64 + l31;
        opart[base]      = (__bf16)oa[0][r];
        opart[base + 32] = (__bf16)oa[1][r];
    }
    if (hi == 0)
        lpart[kz * 65536 + bh * 2048 + q0 + l31] = l_run;
}

// ---------- attention combine: o = (p0+p1) / (l0+l1) ----------
__global__ __launch_bounds__(256) void attn_comb(const __bf16* __restrict__ op,
                                                 const float* __restrict__ lp,
                                                 __bf16* __restrict__ o) {
    const int row = blockIdx.x;            // b*2048 + q
    const int t = threadIdx.x;
    const int b = row >> 11, q = row & 2047;
    const int c0 = t * 4;
    const int h = c0 >> 6;
    const int li = (b * 16 + h) * 2048 + q;
    float l = lp[li] + lp[65536 + li];
    float inv = 1.0f / l;
    bf16x4 p0 = *reinterpret_cast<const bf16x4*>(op + (size_t)row * 1024 + c0);
    bf16x4 p1 = *reinterpret_cast<const bf16x4*>(op + 4194304 + (size_t)row * 1024 + c0);
    bf16x4 o4;
#pragma unroll
    for (int j = 0; j < 4; ++j)
        o4[j] = (__bf16)(((float)p0[j] + (float)p1[j]) * inv);
    *reinterpret_cast<bf16x4*>(o + (size_t)row * 1024 + c0) = o4;
}

// ---------- launch ----------
extern "C" void kernel_launch(void* const* d_in, const int* in_sizes, int n_in,
                              void* d_out, int out_size, void* d_ws, size_t ws_size,
                              hipStream_t stream) {
    const float* x      = (const float*)d_in[0];
    const float* w_qkv  = (const float*)d_in[3];
    const float* w_o    = (const float*)d_in[4];
    const float* w1     = (const float*)d_in[5];
    const float* w2     = (const float*)d_in[6];
    const float* g_attn = (const float*)d_in[7];
    const float* g_ff   = (const float*)d_in[8];
    float* out = (float*)d_out;

    char* ws = (char*)d_ws;
    size_t off = 0;
    auto alloc = [&](size_t bytes) -> void* {
        void* p = ws + off;
        off += (bytes + 255) & ~(size_t)255;
        return p;
    };
    __bf16* wqkv_b = (__bf16*)alloc((size_t)3072 * 1024 * 2);
    __bf16* wo_b   = (__bf16*)alloc((size_t)1024 * 1024 * 2);
    __bf16* w1_b   = (__bf16*)alloc((size_t)8192 * 1024 * 2);
    __bf16* w2_b   = (__bf16*)alloc((size_t)1024 * 4096 * 2);
    __bf16* h_b    = (__bf16*)alloc((size_t)4096 * 1024 * 2);
    __bf16* qkv_b  = (__bf16*)alloc((size_t)4096 * 3072 * 2);
    __bf16* o_b    = (__bf16*)alloc((size_t)4096 * 1024 * 2);
    __bf16* x2b    = (__bf16*)alloc((size_t)4096 * 1024 * 2);
    __bf16* vt_b   = (__bf16*)alloc((size_t)32 * 64 * 2048 * 2);
    __bf16* opart  = (__bf16*)alloc((size_t)2 * 4096 * 1024 * 2);
    float*  lpart  = (float*)alloc((size_t)2 * 32 * 2048 * 4);
    __bf16* act_b  = qkv_b;  // alias: act over qkv (qkv dead after attn)

    cvt4_kernel<<<16384, 256, 0, stream>>>(w_qkv, w_o, w1, w2,
                                           wqkv_b, wo_b, w1_b, w2_b);

    rmsnorm_kernel<<<4096, 256, 0, stream>>>(x, g_attn, h_b);
    // qkv: Q,K -> qkv_b; V transposed -> vt_b (fused)
    gemm_nt<4, 4, 0><<<dim3(32, 24), 256, 0, stream>>>(h_b, 1024, wqkv_b, 1024,
                                                       qkv_b, nullptr, nullptr, nullptr,
                                                       vt_b, 1024, 3072);
    // attention: KV-split-2, fixed-base partials + linear combine
    attn_kernel<<<dim3(16, 32, 2), 256, 0, stream>>>(qkv_b, vt_b, opart, lpart);
    attn_comb<<<4096, 256, 0, stream>>>(opart, lpart, o_b);
    // o-proj: x2b (bf16) = o @ w_o^T + x
    gemm_nt<1, 2, 0><<<dim3(32, 16), 256, 0, stream>>>(o_b, 1024, wo_b, 1024,
                                                       x2b, nullptr, x, nullptr,
                                                       nullptr, 1024, 1024);
    rmsnorm_b_kernel<<<4096, 256, 0, stream>>>(x2b, g_ff, h_b);
    // ffn1: 128x128 tiles + fused SwiGLU, square 16x16 XCD chunks
    gemm_nt<2, 4, 1><<<dim3(32, 64), 256, 0, stream>>>(h_b, 1024, w1_b, 1024,
                                                       act_b, nullptr, nullptr, nullptr,
                                                       nullptr, 1024, 4096);
    // ffn2: 128x64 tiles, 512 blocks, out = act @ w2^T + x2b
    gemm_nt<3, 2, 0><<<dim3(32, 16), 256, 0, stream>>>(act_b, 4096, w2_b, 4096,
                                                       nullptr, out, nullptr, x2b,
                                                       nullptr, 4096, 1024);
}

// Round 15
// 301.652 us; speedup vs baseline: 1.4673x; 1.0197x over previous
//
#include <hip/hip_runtime.h>
#include <cstdint>
#include <cstddef>

// ---------- types ----------
typedef __attribute__((ext_vector_type(8)))  __bf16 bf16x8;
typedef __attribute__((ext_vector_type(4)))  __bf16 bf16x4;
typedef __attribute__((ext_vector_type(4)))  float  f32x4;
typedef __attribute__((ext_vector_type(16))) float  f32x16;
typedef __attribute__((ext_vector_type(2)))  uint32_t u32x2;
typedef __attribute__((ext_vector_type(4)))  uint32_t u32x4;

#define MFMA_BF16(a, b, c) __builtin_amdgcn_mfma_f32_16x16x32_bf16((a), (b), (c), 0, 0, 0)
#define MFMA32(a, b, c)    __builtin_amdgcn_mfma_f32_32x32x16_bf16((a), (b), (c), 0, 0, 0)

// async global->LDS, 16B per lane. LDS dest must be wave-uniform base + lane*16.
__device__ __forceinline__ void gload_lds16(const __bf16* src, __bf16* lds_dst) {
    __builtin_amdgcn_global_load_lds(
        (const __attribute__((address_space(1))) void*)(const_cast<__bf16*>(src)),
        (__attribute__((address_space(3))) void*)(lds_dst), 16, 0, 0);
}

__device__ __forceinline__ uint32_t pack2(float a, float b) {
    uint16_t ua = __builtin_bit_cast(uint16_t, (__bf16)a);
    uint16_t ub = __builtin_bit_cast(uint16_t, (__bf16)b);
    return (uint32_t)ua | ((uint32_t)ub << 16);
}

// XCD-chunked bijective block swizzle (requires n%8==0).
__device__ __forceinline__ int xcd_swz(int lid, int n) {
    return (lid & 7) * (n >> 3) + (lid >> 3);
}

// ---------- fused fp32 -> bf16 convert (all 4 weights, one launch) ----------
__global__ __launch_bounds__(256) void cvt4_kernel(const float* __restrict__ s0,
                                                   const float* __restrict__ s1,
                                                   const float* __restrict__ s2,
                                                   const float* __restrict__ s3,
                                                   __bf16* __restrict__ d0,
                                                   __bf16* __restrict__ d1,
                                                   __bf16* __restrict__ d2,
                                                   __bf16* __restrict__ d3) {
    int b = blockIdx.x;
    const float* s; __bf16* d; int off;
    if (b < 3072)       { s = s0; d = d0; off = b; }
    else if (b < 4096)  { s = s1; d = d1; off = b - 3072; }
    else if (b < 12288) { s = s2; d = d2; off = b - 4096; }
    else                { s = s3; d = d3; off = b - 12288; }
    int i = off * 256 + threadIdx.x;
    float4 v = reinterpret_cast<const float4*>(s)[i];
    bf16x4 o;
    o[0] = (__bf16)v.x; o[1] = (__bf16)v.y; o[2] = (__bf16)v.z; o[3] = (__bf16)v.w;
    reinterpret_cast<bf16x4*>(d)[i] = o;
}

// ---------- RMSNorm (row = 1024 fp32) -> bf16 ----------
__global__ __launch_bounds__(256) void rmsnorm_kernel(const float* __restrict__ x,
                                                      const float* __restrict__ g,
                                                      __bf16* __restrict__ out) {
    const int row = blockIdx.x;
    const int t = threadIdx.x;
    float4 v = reinterpret_cast<const float4*>(x + (size_t)row * 1024)[t];
    float ss = v.x * v.x + v.y * v.y + v.z * v.z + v.w * v.w;
#pragma unroll
    for (int m = 1; m < 64; m <<= 1) ss += __shfl_xor(ss, m);
    __shared__ float sred[4];
    if ((t & 63) == 0) sred[t >> 6] = ss;
    __syncthreads();
    float tot = sred[0] + sred[1] + sred[2] + sred[3];
    float rs = rsqrtf(tot * (1.0f / 1024.0f) + 1.1920928955078125e-07f);
    float4 gv = reinterpret_cast<const float4*>(g)[t];
    bf16x4 o;
    o[0] = (__bf16)(v.x * rs * gv.x);
    o[1] = (__bf16)(v.y * rs * gv.y);
    o[2] = (__bf16)(v.z * rs * gv.z);
    o[3] = (__bf16)(v.w * rs * gv.w);
    *reinterpret_cast<bf16x4*>(out + (size_t)row * 1024 + t * 4) = o;
}

// ---------- RMSNorm (row = 1024 bf16) -> bf16 ----------
__global__ __launch_bounds__(256) void rmsnorm_b_kernel(const __bf16* __restrict__ x,
                                                        const float* __restrict__ g,
                                                        __bf16* __restrict__ out) {
    const int row = blockIdx.x;
    const int t = threadIdx.x;
    bf16x4 v4 = reinterpret_cast<const bf16x4*>(x + (size_t)row * 1024)[t];
    float a = (float)v4[0], b = (float)v4[1], c = (float)v4[2], d = (float)v4[3];
    float ss = a * a + b * b + c * c + d * d;
#pragma unroll
    for (int m = 1; m < 64; m <<= 1) ss += __shfl_xor(ss, m);
    __shared__ float sred[4];
    if ((t & 63) == 0) sred[t >> 6] = ss;
    __syncthreads();
    float tot = sred[0] + sred[1] + sred[2] + sred[3];
    float rs = rsqrtf(tot * (1.0f / 1024.0f) + 1.1920928955078125e-07f);
    float4 gv = reinterpret_cast<const float4*>(g)[t];
    bf16x4 o;
    o[0] = (__bf16)(a * rs * gv.x);
    o[1] = (__bf16)(b * rs * gv.y);
    o[2] = (__bf16)(c * rs * gv.z);
    o[3] = (__bf16)(d * rs * gv.w);
    *reinterpret_cast<bf16x4*>(out + (size_t)row * 1024 + t * 4) = o;
}

// ---------- NT GEMM (16x16x32 MFMA): C[m,n] = sum_k A[m,k] * B[n,k] ----------
// BM = NT/2 (NT=256 -> 128x(NB*32), 4 waves; NT=512 -> 256x(NB*32), 8 waves).
// Per-wave 64 x (NB*16), in-loop address computation (VGPR ~76 — R13 lesson:
// hoisting pointers costs occupancy). 16-row fragment pattern: 0 bank conflicts.
// NT=512 raises arithmetic intensity: 6 instead of 8 gload_lds per thread/K-tile.
// MODE 0: out bf16.
// MODE 1: out bf16 = acc + f32 resid            (o-proj -> x2 bf16)
// MODE 2: FFN1+SwiGLU fused (B rows permuted via srow; pair cols via shfl_xor(1)).
// MODE 3: out f32 = acc + bf16 resid            (ffn2 -> final out)
// MODE 4: qkv: Q,K cols -> outb; V cols (col>=2048) transposed -> vt[bh][hd][n]
// SQ: 1 = square 16x16 XCD chunk mapping (grid 32x64 only), else stripe swizzle.
template <int MODE, int NB, int SQ, int NT>
__global__ __launch_bounds__(NT) void gemm_nt(const __bf16* __restrict__ A, int lda,
                                              const __bf16* __restrict__ B, int ldb,
                                              __bf16* __restrict__ outb,
                                              float* __restrict__ outf,
                                              const float* __restrict__ resid,
                                              const __bf16* __restrict__ residb,
                                              __bf16* __restrict__ vt,
                                              int K, int ldo) {
    constexpr int BN = NB * 32;
    constexpr int BM = NT / 2;
    constexpr int BITER = (BN * 8) / NT;   // B staging iters
    __shared__ __attribute__((aligned(16))) __bf16 As[BM * 64];
    __shared__ __attribute__((aligned(16))) __bf16 Bs[BN * 64];
    const int t = threadIdx.x;
    const int lane = t & 63;
    const int wid = t >> 6;
    int bm, bn;
    if (SQ) {   // square 16x16 chunks per XCD (grid must be 32x64)
        int lid = blockIdx.x + blockIdx.y * gridDim.x;
        int c = lid & 7, i = lid >> 3;
        bm = (c & 1) * 16 + (i & 15);
        bn = (c >> 1) * 16 + (i >> 4);
    } else {
        int nwg = gridDim.x * gridDim.y;
        int sid = xcd_swz(blockIdx.x + blockIdx.y * gridDim.x, nwg);
        bm = sid % gridDim.x; bn = sid / gridDim.x;
    }
    const int wm = (wid >> 1) * 64, wn = (wid & 1) * (NB * 16);
    f32x4 acc[4][NB] = {};

    for (int kt = 0; kt < K; kt += 64) {
        __syncthreads();
#pragma unroll
        for (int i = 0; i < 4; ++i) {          // A tile: BM x 64 (4 iters both NT)
            int L = i * NT + t;
            int r = L >> 3, s = L & 7;
            int c = s ^ (r & 7);
            gload_lds16(A + (size_t)(bm * BM + r) * lda + kt + c * 8, As + L * 8);
        }
#pragma unroll
        for (int i = 0; i < BITER; ++i) {      // B tile: BN x 64
            int L = i * NT + t;
            int r = L >> 3, s = L & 7;
            int c = s ^ (r & 7);
            int rb = bn * BN + r;
            int srow = (MODE == 2) ? ((rb >> 1) + ((rb & 1) << 12)) : rb;
            gload_lds16(B + (size_t)srow * ldb + kt + c * 8, Bs + L * 8);
        }
        __syncthreads();
#pragma unroll
        for (int ks = 0; ks < 2; ++ks) {
            bf16x8 af[4], bfr[NB];
#pragma unroll
            for (int mi = 0; mi < 4; ++mi) {
                int r = wm + mi * 16 + (lane & 15);
                int slot = (ks * 4 + (lane >> 4)) ^ (r & 7);
                af[mi] = *reinterpret_cast<const bf16x8*>(As + r * 64 + slot * 8);
            }
#pragma unroll
            for (int ni = 0; ni < NB; ++ni) {
                int r = wn + ni * 16 + (lane & 15);
                int slot = (ks * 4 + (lane >> 4)) ^ (r & 7);
                bfr[ni] = *reinterpret_cast<const bf16x8*>(Bs + r * 64 + slot * 8);
            }
            __builtin_amdgcn_s_setprio(1);
#pragma unroll
            for (int mi = 0; mi < 4; ++mi)
#pragma unroll
                for (int ni = 0; ni < NB; ++ni)
                    acc[mi][ni] = MFMA_BF16(af[mi], bfr[ni], acc[mi][ni]);
            __builtin_amdgcn_s_setprio(0);
        }
    }
    const int row0 = bm * BM + wm + ((lane >> 4) << 2);
    const int col0 = bn * BN + wn + (lane & 15);
    if (MODE == 4 && col0 >= 2048) {
        // V path: write transposed to vt[bh][hd][n]; rows r2 are consecutive n
#pragma unroll
        for (int mi = 0; mi < 4; ++mi)
#pragma unroll
            for (int ni = 0; ni < NB; ++ni) {
                bf16x4 o4;
#pragma unroll
                for (int r2 = 0; r2 < 4; ++r2) o4[r2] = (__bf16)acc[mi][ni][r2];
                int n0 = row0 + mi * 16;
                int bb = n0 >> 11, nn = n0 & 2047;
                int vc = col0 + ni * 16 - 2048;
                *reinterpret_cast<bf16x4*>(
                    vt + ((size_t)(bb * 16 + (vc >> 6)) * 64 + (vc & 63)) * 2048 + nn) = o4;
            }
        return;
    }
#pragma unroll
    for (int mi = 0; mi < 4; ++mi)
#pragma unroll
        for (int ni = 0; ni < NB; ++ni)
#pragma unroll
            for (int r2 = 0; r2 < 4; ++r2) {
                int row = row0 + mi * 16 + r2;
                int col = col0 + ni * 16;
                float v = acc[mi][ni][r2];
                size_t idx = (size_t)row * ldo + col;
                if (MODE == 0 || MODE == 4) {
                    outb[idx] = (__bf16)v;
                } else if (MODE == 1) {
                    outb[idx] = (__bf16)(v + resid[idx]);
                } else if (MODE == 3) {
                    outf[idx] = v + (float)residb[idx];
                } else {
                    float pv = __shfl_xor(v, 1);
                    if (!(lane & 1)) {
                        float sg = v / (1.0f + __expf(-v));
                        outb[(size_t)row * ldo + (col >> 1)] = (__bf16)(sg * pv);
                    }
                }
            }
}

// ---------- flash attention v5 (R9): fixed-base softmax + KV-split-2 ----------
// grid (16, 32, 2): z = KV half. Single-buffered 32KB LDS (4 blocks/CU).
// Partials are LINEAR (fixed base, no max): opart = sum P*V (bf16), lpart = sum P (f32).
__global__ __launch_bounds__(256) void attn_kernel(const __bf16* __restrict__ qkv,
                                                   const __bf16* __restrict__ vt,
                                                   __bf16* __restrict__ opart,
                                                   float* __restrict__ lpart) {
    __shared__ __attribute__((aligned(16))) __bf16 Ks[128 * 64];
    __shared__ __attribute__((aligned(16))) __bf16 Vs[64 * 128];
    const int t = threadIdx.x;
    const int lane = t & 63;
    const int w = t >> 6;
    const int hi = lane >> 5;
    const int l31 = lane & 31;
    const int nwg = gridDim.x * gridDim.y;
    const int sid = xcd_swz(blockIdx.x + blockIdx.y * gridDim.x, nwg);
    const int qb = sid % gridDim.x;
    const int bh = sid / gridDim.x;
    const int kz = blockIdx.z;
    const int b = bh >> 4, h = bh & 15;
    const __bf16* qp = qkv + (size_t)b * 2048 * 3072 + h * 64;
    const __bf16* kp = qp + 1024;
    const __bf16* vtp = vt + (size_t)bh * 64 * 2048;
    const int q0 = qb * 128 + w * 32;

    const float SC = 0.18033688011112042f;   // (1/8) * log2(e)
    bf16x8 qf[4];
#pragma unroll
    for (int s = 0; s < 4; ++s) {
        bf16x8 raw = *reinterpret_cast<const bf16x8*>(
            qp + (size_t)(q0 + l31) * 3072 + s * 16 + hi * 8);
        bf16x8 sc;
#pragma unroll
        for (int j = 0; j < 8; ++j) sc[j] = (__bf16)((float)raw[j] * SC);
        qf[s] = sc;
    }

    f32x16 oa[2] = {};
    float l_run = 0.0f;

    auto stage = [&](int kt) {
#pragma unroll
        for (int i = 0; i < 4; ++i) {
            int L = i * 256 + t;
            int r = L >> 3, s = L & 7;
            int c = s ^ (r & 7);
            gload_lds16(kp + (size_t)(kt + r) * 3072 + c * 8, &Ks[L * 8]);
        }
#pragma unroll
        for (int i = 0; i < 4; ++i) {
            int L = i * 256 + t;
            int r = L >> 4, s = L & 15;
            int c = s ^ (r & 15);
            gload_lds16(vtp + (size_t)r * 2048 + kt + c * 8, &Vs[L * 8]);
        }
    };

    const int kt0 = kz * 1024;
    for (int kt = kt0; kt < kt0 + 1024; kt += 128) {
        stage(kt);
        asm volatile("s_waitcnt vmcnt(0)\n\ts_barrier" ::: "memory");

#pragma unroll
        for (int h2 = 0; h2 < 2; ++h2) {
            f32x16 st[2];
#pragma unroll
            for (int r = 0; r < 16; ++r) { st[0][r] = -6.0f; st[1][r] = -6.0f; }
            __builtin_amdgcn_s_setprio(1);
#pragma unroll
            for (int s = 0; s < 4; ++s) {
#pragma unroll
                for (int mb = 0; mb < 2; ++mb) {
                    int r = h2 * 64 + mb * 32 + l31;
                    int sl = (s * 2 + hi) ^ (r & 7);
                    bf16x8 kf = *reinterpret_cast<const bf16x8*>(&Ks[r * 64 + sl * 8]);
                    st[mb] = MFMA32(kf, qf[s], st[mb]);
                }
            }
            __builtin_amdgcn_s_setprio(0);

            // fixed-base: P = exp2(st) (st biased by -6 via C-in)
            float ps = 0.0f;
#pragma unroll
            for (int mb = 0; mb < 2; ++mb)
#pragma unroll
                for (int r = 0; r < 16; ++r) {
                    float p = exp2f(st[mb][r]);
                    st[mb][r] = p;
                    ps += p;
                }
            ps += __shfl_xor(ps, 32);
            l_run += ps;

            uint32_t pk[16];
#pragma unroll
            for (int mb = 0; mb < 2; ++mb)
#pragma unroll
                for (int i2 = 0; i2 < 8; ++i2)
                    pk[mb * 8 + i2] = pack2(st[mb][2 * i2], st[mb][2 * i2 + 1]);

            __builtin_amdgcn_s_setprio(1);
#pragma unroll
            for (int s2 = 0; s2 < 4; ++s2) {
                const int I0 = (s2 >> 1) * 8 + (s2 & 1) * 4;
                u32x2 w02 = __builtin_amdgcn_permlane32_swap(pk[I0], pk[I0 + 2], false, false);
                u32x2 w13 = __builtin_amdgcn_permlane32_swap(pk[I0 + 1], pk[I0 + 3], false, false);
                u32x4 fv;
                fv[0] = w02[0]; fv[1] = w13[0]; fv[2] = w02[1]; fv[3] = w13[1];
                bf16x8 pa = __builtin_bit_cast(bf16x8, fv);
#pragma unroll
                for (int nb = 0; nb < 2; ++nb) {
                    int rv = nb * 32 + l31;
                    int ch = h2 * 8 + s2 * 2 + hi;
                    int sl = ch ^ (rv & 15);
                    bf16x8 vf = *reinterpret_cast<const bf16x8*>(&Vs[rv * 128 + sl * 8]);
                    oa[nb] = MFMA32(pa, vf, oa[nb]);
                }
            }
            __builtin_amdgcn_s_setprio(0);
        }
        __syncthreads();   // all reads done before next stage overwrites
    }

    // store UNNORMALIZED partials as bf16 (linear combine later; l stays f32)
#pragma unroll
    for (int r = 0; r < 16; ++r) {
        int crow = (r & 3) + 8 * (r >> 2) + 4 * hi;
        int row = q0 + crow;
        size_t base = (size_t)kz * 4194304 + ((size_t)b * 2048 + row) * 1024 + h * 64 + l31;
        opart[base]      = (__bf16)oa[0][r];
        opart[base + 32] = (__bf16)oa[1][r];
    }
    if (hi == 0)
        lpart[kz * 65536 + bh * 2048 + q0 + l31] = l_run;
}

// ---------- attention combine: o = (p0+p1) / (l0+l1) ----------
__global__ __launch_bounds__(256) void attn_comb(const __bf16* __restrict__ op,
                                                 const float* __restrict__ lp,
                                                 __bf16* __restrict__ o) {
    const int row = blockIdx.x;            // b*2048 + q
    const int t = threadIdx.x;
    const int b = row >> 11, q = row & 2047;
    const int c0 = t * 4;
    const int h = c0 >> 6;
    const int li = (b * 16 + h) * 2048 + q;
    float l = lp[li] + lp[65536 + li];
    float inv = 1.0f / l;
    bf16x4 p0 = *reinterpret_cast<const bf16x4*>(op + (size_t)row * 1024 + c0);
    bf16x4 p1 = *reinterpret_cast<const bf16x4*>(op + 4194304 + (size_t)row * 1024 + c0);
    bf16x4 o4;
#pragma unroll
    for (int j = 0; j < 4; ++j)
        o4[j] = (__bf16)(((float)p0[j] + (float)p1[j]) * inv);
    *reinterpret_cast<bf16x4*>(o + (size_t)row * 1024 + c0) = o4;
}

// ---------- launch ----------
extern "C" void kernel_launch(void* const* d_in, const int* in_sizes, int n_in,
                              void* d_out, int out_size, void* d_ws, size_t ws_size,
                              hipStream_t stream) {
    const float* x      = (const float*)d_in[0];
    const float* w_qkv  = (const float*)d_in[3];
    const float* w_o    = (const float*)d_in[4];
    const float* w1     = (const float*)d_in[5];
    const float* w2     = (const float*)d_in[6];
    const float* g_attn = (const float*)d_in[7];
    const float* g_ff   = (const float*)d_in[8];
    float* out = (float*)d_out;

    char* ws = (char*)d_ws;
    size_t off = 0;
    auto alloc = [&](size_t bytes) -> void* {
        void* p = ws + off;
        off += (bytes + 255) & ~(size_t)255;
        return p;
    };
    __bf16* wqkv_b = (__bf16*)alloc((size_t)3072 * 1024 * 2);
    __bf16* wo_b   = (__bf16*)alloc((size_t)1024 * 1024 * 2);
    __bf16* w1_b   = (__bf16*)alloc((size_t)8192 * 1024 * 2);
    __bf16* w2_b   = (__bf16*)alloc((size_t)1024 * 4096 * 2);
    __bf16* h_b    = (__bf16*)alloc((size_t)4096 * 1024 * 2);
    __bf16* qkv_b  = (__bf16*)alloc((size_t)4096 * 3072 * 2);
    __bf16* o_b    = (__bf16*)alloc((size_t)4096 * 1024 * 2);
    __bf16* x2b    = (__bf16*)alloc((size_t)4096 * 1024 * 2);
    __bf16* vt_b   = (__bf16*)alloc((size_t)32 * 64 * 2048 * 2);
    __bf16* opart  = (__bf16*)alloc((size_t)2 * 4096 * 1024 * 2);
    float*  lpart  = (float*)alloc((size_t)2 * 32 * 2048 * 4);
    __bf16* act_b  = qkv_b;  // alias: act over qkv (qkv dead after attn)

    cvt4_kernel<<<16384, 256, 0, stream>>>(w_qkv, w_o, w1, w2,
                                           wqkv_b, wo_b, w1_b, w2_b);

    rmsnorm_kernel<<<4096, 256, 0, stream>>>(x, g_attn, h_b);
    // qkv: BM=256 (8 waves), Q,K -> qkv_b; V transposed -> vt_b (fused)
    gemm_nt<4, 4, 0, 512><<<dim3(16, 24), 512, 0, stream>>>(h_b, 1024, wqkv_b, 1024,
                                                            qkv_b, nullptr, nullptr, nullptr,
                                                            vt_b, 1024, 3072);
    // attention: KV-split-2, fixed-base partials + linear combine
    attn_kernel<<<dim3(16, 32, 2), 256, 0, stream>>>(qkv_b, vt_b, opart, lpart);
    attn_comb<<<4096, 256, 0, stream>>>(opart, lpart, o_b);
    // o-proj: x2b (bf16) = o @ w_o^T + x
    gemm_nt<1, 2, 0, 256><<<dim3(32, 16), 256, 0, stream>>>(o_b, 1024, wo_b, 1024,
                                                            x2b, nullptr, x, nullptr,
                                                            nullptr, 1024, 1024);
    rmsnorm_b_kernel<<<4096, 256, 0, stream>>>(x2b, g_ff, h_b);
    // ffn1: BM=256 (8 waves) + fused SwiGLU
    gemm_nt<2, 4, 0, 512><<<dim3(16, 64), 512, 0, stream>>>(h_b, 1024, w1_b, 1024,
                                                            act_b, nullptr, nullptr, nullptr,
                                                            nullptr, 1024, 4096);
    // ffn2: 128x64 tiles, 512 blocks, out = act @ w2^T + x2b
    gemm_nt<3, 2, 0, 256><<<dim3(32, 16), 256, 0, stream>>>(act_b, 4096, w2_b, 4096,
                                                            nullptr, out, nullptr, x2b,
                                                            nullptr, 4096, 1024);
}